// Round 1
// baseline (747.283 us; speedup 1.0000x reference)
//
#include <hip/hip_runtime.h>

#define S_LEN 8192
#define D_KK  128
#define KVB   32
#define SCALE 0.08838834764831845f   // 1/sqrt(128)

typedef __bf16 bf16x4 __attribute__((ext_vector_type(4)));
typedef __bf16 bf16x8 __attribute__((ext_vector_type(8)));
typedef float  f32x4  __attribute__((ext_vector_type(4)));

// Flash attention fwd, fp32 in/out, bf16 MFMA 16x16x32.
// Swapped QK^T: compute S^T = K_tile * Q^T so each lane owns ONE q column
// -> m/l online-softmax state is a per-lane scalar (replicated x4 across
// k-groups), row reduction = 2 shfl_xor (16, 32).
// PV as O^T = V^T * P^T: A-operand = V^T tile (transposed during staging),
// B-operand = P read back from per-wave swizzled LDS.
// All LDS tiles XOR-swizzled (G4: row-major D=128 would be a 32-way bank
// conflict on ds_read_b128).
__global__ __launch_bounds__(128) void attn_fwd_23450521436217(
    const float* __restrict__ Q,
    const float* __restrict__ K,
    const float* __restrict__ V,
    float* __restrict__ O)
{
    const int tid  = threadIdx.x;
    const int wave = tid >> 6;
    const int lane = tid & 63;
    const int lq   = lane & 15;   // q column within the wave's 16-row tile
    const int g    = lane >> 4;   // k-group 0..3

    // Kt: [key 0..31][d 0..127], element (k,d) at k*128 + (d ^ ((k&7)<<3))
    // Vt: [d 0..127][key 0..31], element (d,k) at d*32 + (k ^ ((d&3)<<3))
    // Pl: per-wave [q 0..15][key 0..31], element (q,k) at q*32 + (k ^ ((q&6)<<2))
    __shared__ __align__(16) __bf16 Kt[KVB * D_KK];
    __shared__ __align__(16) __bf16 Vt[D_KK * KVB];
    __shared__ __align__(16) __bf16 Pl[2][16 * KVB];

    const int qrow = blockIdx.x * 32 + wave * 16 + lq;

    // Q fragments (B operand): qf[dblk][j] = Q[qrow][dblk*32 + 8g + j]
    bf16x8 qf[4];
    #pragma unroll
    for (int dblk = 0; dblk < 4; ++dblk) {
        const float* qp = Q + (size_t)qrow * D_KK + dblk * 32 + g * 8;
        float4 a = *(const float4*)(qp);
        float4 b = *(const float4*)(qp + 4);
        bf16x8 f;
        f[0]=(__bf16)a.x; f[1]=(__bf16)a.y; f[2]=(__bf16)a.z; f[3]=(__bf16)a.w;
        f[4]=(__bf16)b.x; f[5]=(__bf16)b.y; f[6]=(__bf16)b.z; f[7]=(__bf16)b.w;
        qf[dblk] = f;
    }

    f32x4 oacc[8];
    #pragma unroll
    for (int i = 0; i < 8; ++i) oacc[i] = f32x4{0.f, 0.f, 0.f, 0.f};
    float m_run = -1e30f, l_run = 0.0f;

    const int swzp = (lq & 6) << 2;   // P-tile swizzle for this lane's q row

    for (int kv0 = 0; kv0 < S_LEN; kv0 += KVB) {
        // ---- stage K tile and transposed V tile (fp32 -> bf16) ----
        const float4* kg = (const float4*)(K + (size_t)kv0 * D_KK);
        const float4* vg = (const float4*)(V + (size_t)kv0 * D_KK);
        #pragma unroll
        for (int i = 0; i < 8; ++i) {
            int e4  = i * 128 + tid;        // float4 index into 32x128 tile
            int row = e4 >> 5;              // key
            int col = (e4 & 31) << 2;       // d
            float4 k4 = kg[e4];
            bf16x4 kb;
            kb[0]=(__bf16)k4.x; kb[1]=(__bf16)k4.y; kb[2]=(__bf16)k4.z; kb[3]=(__bf16)k4.w;
            *(bf16x4*)(&Kt[row * D_KK + (col ^ ((row & 7) << 3))]) = kb;
            float4 v4 = vg[e4];
            __bf16 vb[4] = {(__bf16)v4.x, (__bf16)v4.y, (__bf16)v4.z, (__bf16)v4.w};
            #pragma unroll
            for (int mI = 0; mI < 4; ++mI) {
                int d = col + mI;
                Vt[d * KVB + (row ^ ((d & 3) << 3))] = vb[mI];
            }
        }
        __syncthreads();

        // ---- QK^T (swapped): S^T[key][q], two 16-key blocks ----
        f32x4 s0 = f32x4{0.f,0.f,0.f,0.f}, s1 = f32x4{0.f,0.f,0.f,0.f};
        #pragma unroll
        for (int dblk = 0; dblk < 4; ++dblk) {
            int d0 = dblk * 32 + g * 8;
            int k0 = lq;
            int k1 = 16 + lq;
            bf16x8 a0 = *(const bf16x8*)(&Kt[k0 * D_KK + (d0 ^ ((k0 & 7) << 3))]);
            bf16x8 a1 = *(const bf16x8*)(&Kt[k1 * D_KK + (d0 ^ ((k1 & 7) << 3))]);
            s0 = __builtin_amdgcn_mfma_f32_16x16x32_bf16(a0, qf[dblk], s0, 0, 0, 0);
            s1 = __builtin_amdgcn_mfma_f32_16x16x32_bf16(a1, qf[dblk], s1, 0, 0, 0);
        }

        // this lane's scores: q = lq, keys {4g+r, 16+4g+r}
        float s[8];
        #pragma unroll
        for (int r = 0; r < 4; ++r) { s[r] = s0[r] * SCALE; s[4+r] = s1[r] * SCALE; }

        float tmax = s[0];
        #pragma unroll
        for (int j = 1; j < 8; ++j) tmax = fmaxf(tmax, s[j]);
        tmax = fmaxf(tmax, __shfl_xor(tmax, 16));
        tmax = fmaxf(tmax, __shfl_xor(tmax, 32));

        float mnew = fmaxf(m_run, tmax);
        float p[8], psum = 0.f;
        #pragma unroll
        for (int j = 0; j < 8; ++j) { p[j] = __expf(s[j] - mnew); psum += p[j]; }
        psum += __shfl_xor(psum, 16);
        psum += __shfl_xor(psum, 32);

        float alpha = __expf(m_run - mnew);
        l_run = l_run * alpha + psum;
        m_run = mnew;
        #pragma unroll
        for (int i = 0; i < 8; ++i) oacc[i] *= alpha;

        // ---- write P to per-wave LDS, read back as PV B-operand ----
        bf16x4 pb0, pb1;
        #pragma unroll
        for (int r = 0; r < 4; ++r) { pb0[r] = (__bf16)p[r]; pb1[r] = (__bf16)p[4+r]; }
        *(bf16x4*)(&Pl[wave][lq * 32 + (( 4*g      ) ^ swzp)]) = pb0;
        *(bf16x4*)(&Pl[wave][lq * 32 + ((16 + 4*g  ) ^ swzp)]) = pb1;

        bf16x8 pf = *(const bf16x8*)(&Pl[wave][lq * 32 + ((8*g) ^ swzp)]);

        // ---- PV: O^T[d][q] += V^T * P^T, 8 d-blocks of 16 ----
        #pragma unroll
        for (int db = 0; db < 8; ++db) {
            int d = db * 16 + lq;
            bf16x8 vf = *(const bf16x8*)(&Vt[d * KVB + ((8*g) ^ ((d & 3) << 3))]);
            oacc[db] = __builtin_amdgcn_mfma_f32_16x16x32_bf16(vf, pf, oacc[db], 0, 0, 0);
        }
        __syncthreads();
    }

    // ---- epilogue: O[q][d] = O^T / l ----
    float inv = 1.0f / l_run;
    #pragma unroll
    for (int db = 0; db < 8; ++db) {
        #pragma unroll
        for (int r = 0; r < 4; ++r) {
            int d = db * 16 + 4 * g + r;
            O[(size_t)qrow * D_KK + d] = oacc[db][r] * inv;
        }
    }
}

extern "C" void kernel_launch(void* const* d_in, const int* in_sizes, int n_in,
                              void* d_out, int out_size, void* d_ws, size_t ws_size,
                              hipStream_t stream) {
    const float* Q = (const float*)d_in[0];
    const float* K = (const float*)d_in[1];
    const float* V = (const float*)d_in[2];
    float* O = (float*)d_out;
    dim3 grid(S_LEN / 32), block(128);
    hipLaunchKernelGGL(attn_fwd_23450521436217, grid, block, 0, stream, Q, K, V, O);
}

// Round 2
// 243.044 us; speedup vs baseline: 3.0747x; 3.0747x over previous
//
#include <hip/hip_runtime.h>

#define S_LEN 8192
#define D_KK  128
#define KVB   32
#define SCALE 0.08838834764831845f   // 1/sqrt(128)

typedef __bf16 bf16x4 __attribute__((ext_vector_type(4)));
typedef __bf16 bf16x8 __attribute__((ext_vector_type(8)));
typedef float  f32x4  __attribute__((ext_vector_type(4)));

// ---------------------------------------------------------------------------
// Pre-pass: K (fp32 row-major) -> Kb (bf16 row-major [8192][128])
//           V (fp32 row-major) -> Vt (bf16 TRANSPOSED  [128][8192])
// One block per 32 K/V rows. Coalesced reads; transpose through padded LDS.
// ---------------------------------------------------------------------------
__global__ __launch_bounds__(256) void prep_kv_23450521436217(
    const float* __restrict__ K,
    const float* __restrict__ V,
    __bf16* __restrict__ Kb,
    __bf16* __restrict__ Vt)
{
    const int tid = threadIdx.x;
    const int k0  = blockIdx.x * 32;
    __shared__ __bf16 T[32][130];   // +2 pad: stride 65 dwords -> conflict-free cols

    const float4* kg = (const float4*)(K + (size_t)k0 * D_KK);
    const float4* vg = (const float4*)(V + (size_t)k0 * D_KK);
    bf16x4* kb = (bf16x4*)(Kb + (size_t)k0 * D_KK);

    #pragma unroll
    for (int i = 0; i < 4; ++i) {
        int f = tid + i * 256;            // float4 index in 32x128 tile
        float4 a = kg[f];
        bf16x4 b;
        b[0]=(__bf16)a.x; b[1]=(__bf16)a.y; b[2]=(__bf16)a.z; b[3]=(__bf16)a.w;
        kb[f] = b;
        float4 v = vg[f];
        int row = f >> 5, col = (f & 31) << 2;
        T[row][col+0]=(__bf16)v.x; T[row][col+1]=(__bf16)v.y;
        T[row][col+2]=(__bf16)v.z; T[row][col+3]=(__bf16)v.w;
    }
    __syncthreads();

    const int d  = tid >> 1;
    const int ks = (tid & 1) << 4;
    bf16x8 o0, o1;
    #pragma unroll
    for (int j = 0; j < 8; ++j) { o0[j] = T[ks+j][d]; o1[j] = T[ks+8+j][d]; }
    __bf16* dst = Vt + (size_t)d * S_LEN + k0 + ks;
    *(bf16x8*)(dst)     = o0;
    *(bf16x8*)(dst + 8) = o1;
}

// ---------------------------------------------------------------------------
// Flash attention fwd. Block = 512 threads (8 waves), one 16-row q-tile per
// block; each wave owns a 1024-key KV strip (no barriers in the main loop).
// K/V^T fragments loaded directly from the bf16 pre-pass buffers (L2-resident)
// -> zero LDS staging. End-of-block merge of 8 partial (m,l,O^T) in LDS.
// Swapped QK^T (S^T = K*Q^T): per-lane scalar m/l, row-reduce = 2 shfl_xor.
// ---------------------------------------------------------------------------
__global__ __launch_bounds__(512, 4) void attn_fwd_23450521436217(
    const float*  __restrict__ Q,
    const __bf16* __restrict__ Kb,
    const __bf16* __restrict__ Vt,
    float* __restrict__ O)
{
    const int tid  = threadIdx.x;
    const int wave = tid >> 6;    // 0..7
    const int lane = tid & 63;
    const int lq   = lane & 15;   // q column within the 16-row tile
    const int g    = lane >> 4;   // k-group 0..3

    __shared__ __align__(16) __bf16 Pl[8][16 * KVB];  // per-wave P round-trip
    __shared__ float Oacc[D_KK][16];
    __shared__ float Ml[8][16], Ll[8][16], Lf[16];

    const int qrow = blockIdx.x * 16 + lq;

    // Q fragments (B operand): qf[dblk][j] = Q[qrow][dblk*32 + 8g + j]
    bf16x8 qf[4];
    #pragma unroll
    for (int dblk = 0; dblk < 4; ++dblk) {
        const float* qp = Q + (size_t)qrow * D_KK + dblk * 32 + g * 8;
        float4 a = *(const float4*)(qp);
        float4 b = *(const float4*)(qp + 4);
        bf16x8 f;
        f[0]=(__bf16)a.x; f[1]=(__bf16)a.y; f[2]=(__bf16)a.z; f[3]=(__bf16)a.w;
        f[4]=(__bf16)b.x; f[5]=(__bf16)b.y; f[6]=(__bf16)b.z; f[7]=(__bf16)b.w;
        qf[dblk] = f;
    }

    f32x4 oacc[8];
    #pragma unroll
    for (int i = 0; i < 8; ++i) oacc[i] = f32x4{0.f, 0.f, 0.f, 0.f};
    float m_run = -1e30f, l_run = 0.0f;

    const int swzp = (lq & 6) << 2;
    const int kv_base = wave * (S_LEN / 8);

    for (int it = 0; it < (S_LEN / 8) / KVB; ++it) {
        const int kv0 = kv_base + it * KVB;

        // ---- QK^T (swapped): S^T[key][q] ----
        const __bf16* kr0 = Kb + (size_t)(kv0 + lq) * D_KK + g * 8;
        const __bf16* kr1 = kr0 + 16 * D_KK;
        f32x4 s0 = f32x4{0.f,0.f,0.f,0.f}, s1 = f32x4{0.f,0.f,0.f,0.f};
        #pragma unroll
        for (int dblk = 0; dblk < 4; ++dblk) {
            bf16x8 a0 = *(const bf16x8*)(kr0 + dblk * 32);
            bf16x8 a1 = *(const bf16x8*)(kr1 + dblk * 32);
            s0 = __builtin_amdgcn_mfma_f32_16x16x32_bf16(a0, qf[dblk], s0, 0, 0, 0);
            s1 = __builtin_amdgcn_mfma_f32_16x16x32_bf16(a1, qf[dblk], s1, 0, 0, 0);
        }

        // this lane's scores: q = lq, keys {4g+r, 16+4g+r}
        float s[8];
        #pragma unroll
        for (int r = 0; r < 4; ++r) { s[r] = s0[r] * SCALE; s[4+r] = s1[r] * SCALE; }

        float tmax = s[0];
        #pragma unroll
        for (int j = 1; j < 8; ++j) tmax = fmaxf(tmax, s[j]);
        tmax = fmaxf(tmax, __shfl_xor(tmax, 16));
        tmax = fmaxf(tmax, __shfl_xor(tmax, 32));

        float mnew = fmaxf(m_run, tmax);
        float p[8], psum = 0.f;
        #pragma unroll
        for (int j = 0; j < 8; ++j) { p[j] = __expf(s[j] - mnew); psum += p[j]; }
        psum += __shfl_xor(psum, 16);
        psum += __shfl_xor(psum, 32);

        float alpha = __expf(m_run - mnew);
        l_run = l_run * alpha + psum;
        m_run = mnew;
        #pragma unroll
        for (int i = 0; i < 8; ++i) oacc[i] *= alpha;

        // ---- P round-trip through per-wave LDS (B operand for PV) ----
        bf16x4 pb0, pb1;
        #pragma unroll
        for (int r = 0; r < 4; ++r) { pb0[r] = (__bf16)p[r]; pb1[r] = (__bf16)p[4+r]; }
        *(bf16x4*)(&Pl[wave][lq * 32 + (( 4*g     ) ^ swzp)]) = pb0;
        *(bf16x4*)(&Pl[wave][lq * 32 + ((16 + 4*g ) ^ swzp)]) = pb1;
        bf16x8 pf = *(const bf16x8*)(&Pl[wave][lq * 32 + ((8*g) ^ swzp)]);

        // ---- PV: O^T[d][q] += V^T * P^T (A operand straight from global) ----
        const __bf16* vr = Vt + (size_t)lq * S_LEN + kv0 + g * 8;
        #pragma unroll
        for (int db = 0; db < 8; ++db) {
            bf16x8 vf = *(const bf16x8*)(vr + (size_t)db * 16 * S_LEN);
            oacc[db] = __builtin_amdgcn_mfma_f32_16x16x32_bf16(vf, pf, oacc[db], 0, 0, 0);
        }
    }

    // ---- merge the 8 per-wave partials ----
    if (g == 0) { Ml[wave][lq] = m_run; Ll[wave][lq] = l_run; }
    __syncthreads();

    float M = -1e30f;
    #pragma unroll
    for (int w = 0; w < 8; ++w) M = fmaxf(M, Ml[w][lq]);
    float L = 0.f;
    #pragma unroll
    for (int w = 0; w < 8; ++w) L += Ll[w][lq] * __expf(Ml[w][lq] - M);
    if (wave == 0 && g == 0) Lf[lq] = L;

    const float scale = __expf(m_run - M);
    #pragma unroll
    for (int i = 0; i < 8; ++i) oacc[i] *= scale;

    for (int r = 0; r < 8; ++r) {
        if (wave == r) {
            #pragma unroll
            for (int db = 0; db < 8; ++db)
                #pragma unroll
                for (int rr = 0; rr < 4; ++rr) {
                    int d = db * 16 + 4 * g + rr;
                    if (r == 0) Oacc[d][lq]  = oacc[db][rr];
                    else        Oacc[d][lq] += oacc[db][rr];
                }
        }
        __syncthreads();
    }

    // ---- write O[q][d] (coalesced float4) ----
    const int q  = tid >> 5;
    const int d0 = (tid & 31) << 2;
    const float invl = 1.0f / Lf[q];
    float4 o;
    o.x = Oacc[d0+0][q] * invl;
    o.y = Oacc[d0+1][q] * invl;
    o.z = Oacc[d0+2][q] * invl;
    o.w = Oacc[d0+3][q] * invl;
    *(float4*)(O + (size_t)(blockIdx.x * 16 + q) * D_KK + d0) = o;
}

extern "C" void kernel_launch(void* const* d_in, const int* in_sizes, int n_in,
                              void* d_out, int out_size, void* d_ws, size_t ws_size,
                              hipStream_t stream) {
    const float* Q = (const float*)d_in[0];
    const float* K = (const float*)d_in[1];
    const float* V = (const float*)d_in[2];
    float* O = (float*)d_out;

    __bf16* Kb = (__bf16*)d_ws;                                   // 2 MB
    __bf16* Vt = (__bf16*)((char*)d_ws + (size_t)S_LEN*D_KK*2);   // 2 MB

    hipLaunchKernelGGL(prep_kv_23450521436217, dim3(S_LEN/32), dim3(256), 0, stream,
                       K, V, Kb, Vt);
    hipLaunchKernelGGL(attn_fwd_23450521436217, dim3(S_LEN/16), dim3(512), 0, stream,
                       Q, Kb, Vt, O);
}

// Round 3
// 133.916 us; speedup vs baseline: 5.5802x; 1.8149x over previous
//
#include <hip/hip_runtime.h>

#define S_LEN 8192
#define D_KK  128
#define SCALE 0.08838834764831845f   // 1/sqrt(128)

typedef __bf16 bf16x2 __attribute__((ext_vector_type(2)));
typedef __bf16 bf16x4 __attribute__((ext_vector_type(4)));
typedef __bf16 bf16x8 __attribute__((ext_vector_type(8)));
typedef float  f32x16 __attribute__((ext_vector_type(16)));

// ---------------------------------------------------------------------------
// Pre-pass (unchanged from round 2): K fp32 -> Kb bf16 row-major [8192][128],
// V fp32 -> Vt bf16 transposed [128][8192].
// ---------------------------------------------------------------------------
__global__ __launch_bounds__(256) void prep_kv_23450521436217(
    const float* __restrict__ K,
    const float* __restrict__ V,
    __bf16* __restrict__ Kb,
    __bf16* __restrict__ Vt)
{
    const int tid = threadIdx.x;
    const int k0  = blockIdx.x * 32;
    __shared__ __bf16 T[32][130];

    const float4* kg = (const float4*)(K + (size_t)k0 * D_KK);
    const float4* vg = (const float4*)(V + (size_t)k0 * D_KK);
    bf16x4* kb = (bf16x4*)(Kb + (size_t)k0 * D_KK);

    #pragma unroll
    for (int i = 0; i < 4; ++i) {
        int f = tid + i * 256;
        float4 a = kg[f];
        bf16x4 b;
        b[0]=(__bf16)a.x; b[1]=(__bf16)a.y; b[2]=(__bf16)a.z; b[3]=(__bf16)a.w;
        kb[f] = b;
        float4 v = vg[f];
        int row = f >> 5, col = (f & 31) << 2;
        T[row][col+0]=(__bf16)v.x; T[row][col+1]=(__bf16)v.y;
        T[row][col+2]=(__bf16)v.z; T[row][col+3]=(__bf16)v.w;
    }
    __syncthreads();

    const int d  = tid >> 1;
    const int ks = (tid & 1) << 4;
    bf16x8 o0, o1;
    #pragma unroll
    for (int j = 0; j < 8; ++j) { o0[j] = T[ks+j][d]; o1[j] = T[ks+8+j][d]; }
    __bf16* dst = Vt + (size_t)d * S_LEN + k0 + ks;
    *(bf16x8*)(dst)     = o0;
    *(bf16x8*)(dst + 8) = o1;
}

// ---------------------------------------------------------------------------
// Flash attention fwd, 32x32x16 MFMA. 256 blocks x 512 thr (1 block/CU,
// 2 waves/SIMD). Each block: 32 q-rows; each of 8 waves: a 1024-key strip,
// 32 iterations of 32 keys. No LDS and no barriers in the main loop:
//  - K double-buffered in registers (prefetch it+1 after QK^T consumes it)
//  - V fragments for iter it issued at loop top (hidden under QK^T+softmax)
//  - P redistributed in-register: bf16 packs + 4x v_permlane32_swap_b32
//  - defer-max (THR=8) skips the 64-reg O rescale on most iterations
// End-of-block merge of 8 partials (m,l,O^T) through LDS.
// ---------------------------------------------------------------------------
__global__ __launch_bounds__(512, 2) void attn_fwd_23450521436217(
    const float*  __restrict__ Q,
    const __bf16* __restrict__ Kb,
    const __bf16* __restrict__ Vt,
    float* __restrict__ O)
{
    const int tid  = threadIdx.x;
    const int wave = tid >> 6;    // 0..7 -> KV strip
    const int lane = tid & 63;
    const int l5   = lane & 31;   // q column (B ops) / A row (K,V ops)
    const int hi   = lane >> 5;   // k-half within MFMA

    __shared__ float Oacc[D_KK][33];          // +1 pad: epilogue column reads
    __shared__ float Ml[8][32], Ll[8][32], Lf[32];

    const int qrow = blockIdx.x * 32 + l5;

    // Q fragments (B operand), SCALE folded in:
    // qf[slab][j] = Q[qrow][slab*16 + hi*8 + j] * SCALE
    bf16x8 qf[8];
    #pragma unroll
    for (int s = 0; s < 8; ++s) {
        const float* qp = Q + (size_t)qrow * D_KK + s * 16 + hi * 8;
        float4 a = *(const float4*)(qp);
        float4 b = *(const float4*)(qp + 4);
        bf16x8 f;
        f[0]=(__bf16)(a.x*SCALE); f[1]=(__bf16)(a.y*SCALE);
        f[2]=(__bf16)(a.z*SCALE); f[3]=(__bf16)(a.w*SCALE);
        f[4]=(__bf16)(b.x*SCALE); f[5]=(__bf16)(b.y*SCALE);
        f[6]=(__bf16)(b.z*SCALE); f[7]=(__bf16)(b.w*SCALE);
        qf[s] = f;
    }

    f32x16 oacc[4];
    #pragma unroll
    for (int d = 0; d < 4; ++d) oacc[d] = f32x16{};
    float m_run = -1e30f, l_run = 0.0f;

    const int kv_base = wave * (S_LEN / 8);
    const __bf16* kp = Kb + (size_t)(kv_base + l5) * D_KK + hi * 8;
    const __bf16* vp = Vt + (size_t)l5 * S_LEN + kv_base + hi * 8;

    bf16x8 kbufA[8], kbufB[8], vb[8];

    // preload K for iter 0
    #pragma unroll
    for (int s = 0; s < 8; ++s) kbufA[s] = *(const bf16x8*)(kp + s * 16);

#define ATTN_BODY(KC, KN, IT, PF)                                              \
    {                                                                          \
        const size_t kvo = (size_t)(IT) * 32;                                  \
        /* V fragments for this iter: A[row=d'][k=16s+8hi+j] from Vt */        \
        _Pragma("unroll")                                                      \
        for (int d = 0; d < 4; ++d) {                                          \
            vb[2*d+0] = *(const bf16x8*)(vp + (size_t)d*32*S_LEN + kvo);       \
            vb[2*d+1] = *(const bf16x8*)(vp + (size_t)d*32*S_LEN + kvo + 16);  \
        }                                                                      \
        /* QK^T swapped: S^T[key][q], key=(r&3)+8*(r>>2)+4*hi, q=l5 */         \
        f32x16 c = f32x16{};                                                   \
        _Pragma("unroll")                                                      \
        for (int s = 0; s < 8; ++s)                                            \
            c = __builtin_amdgcn_mfma_f32_32x32x16_bf16(KC[s], qf[s], c,       \
                                                        0, 0, 0);             \
        /* prefetch next-iter K while softmax runs */                          \
        if (PF) {                                                              \
            const __bf16* kn = kp + (kvo + 32) * D_KK;                         \
            _Pragma("unroll")                                                  \
            for (int s = 0; s < 8; ++s)                                        \
                KN[s] = *(const bf16x8*)(kn + s * 16);                         \
        }                                                                      \
        /* online softmax, per-lane scalar state (defer-max THR=8) */          \
        float tmax = c[0];                                                     \
        _Pragma("unroll")                                                      \
        for (int r = 1; r < 16; ++r) tmax = fmaxf(tmax, c[r]);                 \
        tmax = fmaxf(tmax, __shfl_xor(tmax, 32));                              \
        if (__any(tmax > m_run + 8.0f)) {                                      \
            float mnew  = fmaxf(m_run, tmax);                                  \
            float alpha = __expf(m_run - mnew);                                \
            _Pragma("unroll")                                                  \
            for (int d = 0; d < 4; ++d) oacc[d] *= alpha;                      \
            l_run *= alpha;                                                    \
            m_run  = mnew;                                                     \
        }                                                                      \
        float p[16], ps = 0.0f;                                                \
        _Pragma("unroll")                                                      \
        for (int r = 0; r < 16; ++r) { p[r] = __expf(c[r] - m_run); ps += p[r]; } \
        ps += __shfl_xor(ps, 32);                                              \
        l_run += ps;                                                           \
        /* P -> bf16 packs; permlane32_swap -> PV B-operand words */           \
        unsigned pk[8];                                                        \
        _Pragma("unroll")                                                      \
        for (int t = 0; t < 8; ++t) {                                          \
            bf16x2 w; w[0] = (__bf16)p[2*t]; w[1] = (__bf16)p[2*t+1];          \
            pk[t] = __builtin_bit_cast(unsigned, w);                           \
        }                                                                      \
        asm volatile("v_permlane32_swap_b32 %0, %1" : "+v"(pk[0]), "+v"(pk[2]));\
        asm volatile("v_permlane32_swap_b32 %0, %1" : "+v"(pk[1]), "+v"(pk[3]));\
        asm volatile("v_permlane32_swap_b32 %0, %1" : "+v"(pk[4]), "+v"(pk[6]));\
        asm volatile("v_permlane32_swap_b32 %0, %1" : "+v"(pk[5]), "+v"(pk[7]));\
        union { unsigned u[4]; bf16x8 f; } b0, b1;                             \
        b0.u[0]=pk[0]; b0.u[1]=pk[1]; b0.u[2]=pk[2]; b0.u[3]=pk[3];            \
        b1.u[0]=pk[4]; b1.u[1]=pk[5]; b1.u[2]=pk[6]; b1.u[3]=pk[7];            \
        /* PV: O^T[d][q] += V^T * P^T */                                       \
        _Pragma("unroll")                                                      \
        for (int d = 0; d < 4; ++d) {                                          \
            oacc[d] = __builtin_amdgcn_mfma_f32_32x32x16_bf16(vb[2*d+0], b0.f, \
                                                              oacc[d], 0,0,0); \
            oacc[d] = __builtin_amdgcn_mfma_f32_32x32x16_bf16(vb[2*d+1], b1.f, \
                                                              oacc[d], 0,0,0); \
        }                                                                      \
    }

    for (int it = 0; it < 32; it += 2) {
        ATTN_BODY(kbufA, kbufB, it,     1);
        ATTN_BODY(kbufB, kbufA, it + 1, (it + 2 < 32));
    }
#undef ATTN_BODY

    // ---- merge 8 per-wave partials ----
    if (lane < 32) { Ml[wave][lane] = m_run; Ll[wave][lane] = l_run; }
    __syncthreads();

    float M = Ml[0][l5];
    #pragma unroll
    for (int w = 1; w < 8; ++w) M = fmaxf(M, Ml[w][l5]);
    float L = 0.0f;
    #pragma unroll
    for (int w = 0; w < 8; ++w) L += Ll[w][l5] * __expf(Ml[w][l5] - M);
    if (tid < 32) Lf[tid] = L;

    const float wscale = __expf(m_run - M);

    for (int r = 0; r < 8; ++r) {
        if (wave == r) {
            #pragma unroll
            for (int d = 0; d < 4; ++d)
                #pragma unroll
                for (int reg = 0; reg < 16; ++reg) {
                    int drow = d * 32 + (reg & 3) + 8 * (reg >> 2) + 4 * hi;
                    float v = oacc[d][reg] * wscale;
                    if (r == 0) Oacc[drow][l5]  = v;
                    else        Oacc[drow][l5] += v;
                }
        }
        __syncthreads();
    }

    // ---- write O[q][d], coalesced 2x float4 per thread ----
    const int q  = tid >> 4;            // 0..31
    const int d0 = (tid & 15) * 8;
    const float invl = 1.0f / Lf[q];
    float4 o1, o2;
    o1.x = Oacc[d0+0][q] * invl; o1.y = Oacc[d0+1][q] * invl;
    o1.z = Oacc[d0+2][q] * invl; o1.w = Oacc[d0+3][q] * invl;
    o2.x = Oacc[d0+4][q] * invl; o2.y = Oacc[d0+5][q] * invl;
    o2.z = Oacc[d0+6][q] * invl; o2.w = Oacc[d0+7][q] * invl;
    float* op = O + (size_t)(blockIdx.x * 32 + q) * D_KK + d0;
    *(float4*)(op)     = o1;
    *(float4*)(op + 4) = o2;
}

extern "C" void kernel_launch(void* const* d_in, const int* in_sizes, int n_in,
                              void* d_out, int out_size, void* d_ws, size_t ws_size,
                              hipStream_t stream) {
    const float* Q = (const float*)d_in[0];
    const float* K = (const float*)d_in[1];
    const float* V = (const float*)d_in[2];
    float* O = (float*)d_out;

    __bf16* Kb = (__bf16*)d_ws;                                   // 2 MB
    __bf16* Vt = (__bf16*)((char*)d_ws + (size_t)S_LEN*D_KK*2);   // 2 MB

    hipLaunchKernelGGL(prep_kv_23450521436217, dim3(S_LEN/32), dim3(256), 0, stream,
                       K, V, Kb, Vt);
    hipLaunchKernelGGL(attn_fwd_23450521436217, dim3(S_LEN/32), dim3(512), 0, stream,
                       Q, Kb, Vt, O);
}

// Round 5
// 65.152 us; speedup vs baseline: 11.4699x; 2.0555x over previous
//
#include <hip/hip_runtime.h>

#define S_LEN 8192
#define D_KK  128
#define SCALE 0.08838834764831845f   // 1/sqrt(128)

typedef __bf16 bf16x2 __attribute__((ext_vector_type(2)));
typedef __bf16 bf16x4 __attribute__((ext_vector_type(4)));
typedef __bf16 bf16x8 __attribute__((ext_vector_type(8)));
typedef float  f32x16 __attribute__((ext_vector_type(16)));

// ---------------------------------------------------------------------------
// Pre-pass: pack K and V into FRAGMENT-ORDER bf16 layouts so every main-loop
// wave load is a contiguous 1KB (lane-linear) read:
//   Kf[t*8+s][lane*8+j] = K[t*32 + (lane&31)][s*16 + (lane>>5)*8 + j]
//   Vf[t*8+f][lane*8+j] = V[t*32 + 16*(f&1) + 8*(lane>>5) + j][32*(f>>1) + (lane&31)]
// (t = 32-key tile, s = QK^T k-slab, f = 2*dblock + khalf for PV.)
// One block per tile; V transposed through padded LDS.
// ---------------------------------------------------------------------------
__global__ __launch_bounds__(256) void prep_kv_23450521436217(
    const float* __restrict__ K,
    const float* __restrict__ V,
    __bf16* __restrict__ Kf,
    __bf16* __restrict__ Vf)
{
    const int tid = threadIdx.x;
    const int t   = blockIdx.x;
    __shared__ __bf16 T[32][140];   // pad: 8-row stride shifts banks by 16

    const float* ktile = K + (size_t)t * 32 * D_KK;
    const float* vtile = V + (size_t)t * 32 * D_KK;

    // ---- K: read row chunks, pack to fragment order ----
    const int row = tid & 31;
    const int cp  = tid >> 5;            // 0..7
    #pragma unroll
    for (int i = 0; i < 2; ++i) {
        int c = cp * 2 + i;              // 8-element chunk 0..15
        int s = c >> 1, hi = c & 1;
        const float* src = ktile + row * D_KK + c * 8;
        float4 a = *(const float4*)(src);
        float4 b = *(const float4*)(src + 4);
        bf16x8 o;
        o[0]=(__bf16)a.x; o[1]=(__bf16)a.y; o[2]=(__bf16)a.z; o[3]=(__bf16)a.w;
        o[4]=(__bf16)b.x; o[5]=(__bf16)b.y; o[6]=(__bf16)b.z; o[7]=(__bf16)b.w;
        *(bf16x8*)(Kf + (size_t)(t * 8 + s) * 512 + hi * 256 + row * 8) = o;
    }

    // ---- V: coalesced load -> LDS bf16 ----
    #pragma unroll
    for (int i = 0; i < 4; ++i) {
        int f4 = tid + i * 256;          // float4 id in 32x128 tile
        float4 v = ((const float4*)vtile)[f4];
        int r = f4 >> 5, cc = (f4 & 31) << 2;
        bf16x4 b;
        b[0]=(__bf16)v.x; b[1]=(__bf16)v.y; b[2]=(__bf16)v.z; b[3]=(__bf16)v.w;
        *(bf16x4*)(&T[r][cc]) = b;
    }
    __syncthreads();

    // ---- V: transpose-gather -> fragment order ----
    #pragma unroll
    for (int i = 0; i < 2; ++i) {
        int idx  = tid + i * 256;        // 0..511
        int frag = idx >> 6, lane = idx & 63;
        int hi = lane >> 5, l5 = lane & 31;
        int d = frag >> 1, h = frag & 1;
        bf16x8 o;
        #pragma unroll
        for (int j = 0; j < 8; ++j) o[j] = T[16 * h + 8 * hi + j][32 * d + l5];
        *(bf16x8*)(Vf + (size_t)(t * 8 + frag) * 512 + lane * 8) = o;
    }
}

// ---------------------------------------------------------------------------
// Flash attention fwd, 32x32x16 MFMA. 256 blocks x 512 thr (1 block/CU).
// Each block: 32 q-rows; each of 8 waves: a 1024-key strip, 32 iters of 32
// keys. No LDS / no barriers in the main loop; K double-buffered in regs,
// V issued at loop top; P redistributed via 4x v_permlane32_swap_b32;
// defer-max (THR=8). All K/V loads are contiguous 1KB wave reads from the
// fragment-packed buffers.
// ---------------------------------------------------------------------------
__global__ __launch_bounds__(512, 2) void attn_fwd_23450521436217(
    const float*  __restrict__ Q,
    const __bf16* __restrict__ Kf,
    const __bf16* __restrict__ Vf,
    float* __restrict__ O)
{
    const int tid  = threadIdx.x;
    const int wave = tid >> 6;    // 0..7 -> KV strip
    const int lane = tid & 63;
    const int l5   = lane & 31;   // q column (B ops) / A row (K,V ops)
    const int hi   = lane >> 5;   // k-half within MFMA

    __shared__ float Oacc[D_KK][33];
    __shared__ float Ml[8][32], Ll[8][32], Lf[32];

    const int qrow = blockIdx.x * 32 + l5;

    // Q fragments (B operand), SCALE folded in
    bf16x8 qf[8];
    #pragma unroll
    for (int s = 0; s < 8; ++s) {
        const float* qp = Q + (size_t)qrow * D_KK + s * 16 + hi * 8;
        float4 a = *(const float4*)(qp);
        float4 b = *(const float4*)(qp + 4);
        bf16x8 f;
        f[0]=(__bf16)(a.x*SCALE); f[1]=(__bf16)(a.y*SCALE);
        f[2]=(__bf16)(a.z*SCALE); f[3]=(__bf16)(a.w*SCALE);
        f[4]=(__bf16)(b.x*SCALE); f[5]=(__bf16)(b.y*SCALE);
        f[6]=(__bf16)(b.z*SCALE); f[7]=(__bf16)(b.w*SCALE);
        qf[s] = f;
    }

    f32x16 oacc[4];
    #pragma unroll
    for (int d = 0; d < 4; ++d) oacc[d] = f32x16{};
    float m_run = -1e30f, l_run = 0.0f;

    // fragment-packed bases for this wave's strip (tile stride = 8*512 = 4096)
    const __bf16* kfp = Kf + (size_t)(wave * 32) * 4096 + lane * 8;
    const __bf16* vfp = Vf + (size_t)(wave * 32) * 4096 + lane * 8;

    bf16x8 kbufA[8], kbufB[8], vb[8];

    // preload K for iter 0
    #pragma unroll
    for (int s = 0; s < 8; ++s) kbufA[s] = *(const bf16x8*)(kfp + s * 512);

#define ATTN_BODY(KC, KN, IT, PF)                                              \
    {                                                                          \
        const __bf16* vt = vfp + (size_t)(IT) * 4096;                          \
        _Pragma("unroll")                                                      \
        for (int f = 0; f < 8; ++f)                                            \
            vb[f] = *(const bf16x8*)(vt + f * 512);                            \
        /* QK^T swapped: S^T[key][q], key=(r&3)+8*(r>>2)+4*hi, q=l5 */         \
        f32x16 c = f32x16{};                                                   \
        _Pragma("unroll")                                                      \
        for (int s = 0; s < 8; ++s)                                            \
            c = __builtin_amdgcn_mfma_f32_32x32x16_bf16(KC[s], qf[s], c,       \
                                                        0, 0, 0);             \
        /* prefetch next-iter K while softmax runs */                          \
        if (PF) {                                                              \
            const __bf16* kn = kfp + (size_t)((IT) + 1) * 4096;                \
            _Pragma("unroll")                                                  \
            for (int s = 0; s < 8; ++s)                                        \
                KN[s] = *(const bf16x8*)(kn + s * 512);                        \
        }                                                                      \
        /* online softmax, per-lane scalar state (defer-max THR=8) */          \
        float tmax = c[0];                                                     \
        _Pragma("unroll")                                                      \
        for (int r = 1; r < 16; ++r) tmax = fmaxf(tmax, c[r]);                 \
        tmax = fmaxf(tmax, __shfl_xor(tmax, 32));                              \
        if (__any(tmax > m_run + 8.0f)) {                                      \
            float mnew  = fmaxf(m_run, tmax);                                  \
            float alpha = __expf(m_run - mnew);                                \
            _Pragma("unroll")                                                  \
            for (int d = 0; d < 4; ++d) oacc[d] *= alpha;                      \
            l_run *= alpha;                                                    \
            m_run  = mnew;                                                     \
        }                                                                      \
        float p[16], ps = 0.0f;                                                \
        _Pragma("unroll")                                                      \
        for (int r = 0; r < 16; ++r) { p[r] = __expf(c[r] - m_run); ps += p[r]; } \
        ps += __shfl_xor(ps, 32);                                              \
        l_run += ps;                                                           \
        /* P -> bf16 packs; permlane32_swap -> PV B-operand words */           \
        unsigned pk[8];                                                        \
        _Pragma("unroll")                                                      \
        for (int tq = 0; tq < 8; ++tq) {                                       \
            bf16x2 w; w[0] = (__bf16)p[2*tq]; w[1] = (__bf16)p[2*tq+1];        \
            pk[tq] = __builtin_bit_cast(unsigned, w);                          \
        }                                                                      \
        asm volatile("v_permlane32_swap_b32 %0, %1" : "+v"(pk[0]), "+v"(pk[2]));\
        asm volatile("v_permlane32_swap_b32 %0, %1" : "+v"(pk[1]), "+v"(pk[3]));\
        asm volatile("v_permlane32_swap_b32 %0, %1" : "+v"(pk[4]), "+v"(pk[6]));\
        asm volatile("v_permlane32_swap_b32 %0, %1" : "+v"(pk[5]), "+v"(pk[7]));\
        union { unsigned u[4]; bf16x8 f; } b0, b1;                             \
        b0.u[0]=pk[0]; b0.u[1]=pk[1]; b0.u[2]=pk[2]; b0.u[3]=pk[3];            \
        b1.u[0]=pk[4]; b1.u[1]=pk[5]; b1.u[2]=pk[6]; b1.u[3]=pk[7];            \
        /* PV: O^T[d][q] += V^T * P^T */                                       \
        _Pragma("unroll")                                                      \
        for (int d = 0; d < 4; ++d) {                                          \
            oacc[d] = __builtin_amdgcn_mfma_f32_32x32x16_bf16(vb[2*d+0], b0.f, \
                                                              oacc[d], 0,0,0); \
            oacc[d] = __builtin_amdgcn_mfma_f32_32x32x16_bf16(vb[2*d+1], b1.f, \
                                                              oacc[d], 0,0,0); \
        }                                                                      \
    }

    for (int it = 0; it < 32; it += 2) {
        ATTN_BODY(kbufA, kbufB, it,     1);
        ATTN_BODY(kbufB, kbufA, it + 1, (it + 2 < 32));
    }
#undef ATTN_BODY

    // ---- merge 8 per-wave partials ----
    if (lane < 32) { Ml[wave][lane] = m_run; Ll[wave][lane] = l_run; }
    __syncthreads();

    float M = Ml[0][l5];
    #pragma unroll
    for (int w = 1; w < 8; ++w) M = fmaxf(M, Ml[w][l5]);
    float L = 0.0f;
    #pragma unroll
    for (int w = 0; w < 8; ++w) L += Ll[w][l5] * __expf(Ml[w][l5] - M);
    if (tid < 32) Lf[tid] = L;

    const float wscale = __expf(m_run - M);

    for (int r = 0; r < 8; ++r) {
        if (wave == r) {
            #pragma unroll
            for (int d = 0; d < 4; ++d)
                #pragma unroll
                for (int reg = 0; reg < 16; ++reg) {
                    int drow = d * 32 + (reg & 3) + 8 * (reg >> 2) + 4 * hi;
                    float v = oacc[d][reg] * wscale;
                    if (r == 0) Oacc[drow][l5]  = v;
                    else        Oacc[drow][l5] += v;
                }
        }
        __syncthreads();
    }

    // ---- write O[q][d], coalesced 2x float4 per thread ----
    const int q  = tid >> 4;            // 0..31
    const int d0 = (tid & 15) * 8;
    const float invl = 1.0f / Lf[q];
    float4 o1, o2;
    o1.x = Oacc[d0+0][q] * invl; o1.y = Oacc[d0+1][q] * invl;
    o1.z = Oacc[d0+2][q] * invl; o1.w = Oacc[d0+3][q] * invl;
    o2.x = Oacc[d0+4][q] * invl; o2.y = Oacc[d0+5][q] * invl;
    o2.z = Oacc[d0+6][q] * invl; o2.w = Oacc[d0+7][q] * invl;
    float* op = O + (size_t)(blockIdx.x * 32 + q) * D_KK + d0;
    *(float4*)(op)     = o1;
    *(float4*)(op + 4) = o2;
}

extern "C" void kernel_launch(void* const* d_in, const int* in_sizes, int n_in,
                              void* d_out, int out_size, void* d_ws, size_t ws_size,
                              hipStream_t stream) {
    const float* Q = (const float*)d_in[0];
    const float* K = (const float*)d_in[1];
    const float* V = (const float*)d_in[2];
    float* O = (float*)d_out;

    __bf16* Kf = (__bf16*)d_ws;                                   // 2 MB
    __bf16* Vf = (__bf16*)((char*)d_ws + (size_t)S_LEN*D_KK*2);   // 2 MB

    hipLaunchKernelGGL(prep_kv_23450521436217, dim3(S_LEN/32), dim3(256), 0, stream,
                       K, V, Kf, Vf);
    hipLaunchKernelGGL(attn_fwd_23450521436217, dim3(S_LEN/32), dim3(512), 0, stream,
                       Q, Kf, Vf, O);
}